// Round 4
// baseline (382.736 us; speedup 1.0000x reference)
//
#include <hip/hip_runtime.h>
#include <hip/hip_bf16.h>
#include <stdint.h>

typedef __attribute__((ext_vector_type(8))) short short8;  // 8 bf16 (4 VGPRs)
typedef __attribute__((ext_vector_type(4))) float f32x4;   // 4 fp32 acc

__device__ __forceinline__ uint16_t f2bf(float f) {
    union { float f; uint32_t u; } v; v.f = f;
    uint32_t r = v.u + 0x7FFF + ((v.u >> 16) & 1);  // RNE
    return (uint16_t)(r >> 16);
}
__device__ __forceinline__ float bf2f(uint16_t u) {
    union { uint32_t u; float f; } v; v.u = ((uint32_t)u) << 16;
    return v.f;
}

// Load 8 consecutive elements at flat offset `off`, return packed bf16x8.
// F32=1: source is float* (convert); F32=0: source is bf16/uint16*.
template<int F32>
__device__ __forceinline__ uint4 load8(const void* p, size_t off) {
    if (F32) {
        const float* f = (const float*)p + off;
        float4 f0 = *(const float4*)f;
        float4 f1 = *(const float4*)(f + 4);
        uint4 r;
        r.x = (uint32_t)f2bf(f0.x) | ((uint32_t)f2bf(f0.y) << 16);
        r.y = (uint32_t)f2bf(f0.z) | ((uint32_t)f2bf(f0.w) << 16);
        r.z = (uint32_t)f2bf(f1.x) | ((uint32_t)f2bf(f1.y) << 16);
        r.w = (uint32_t)f2bf(f1.z) | ((uint32_t)f2bf(f1.w) << 16);
        return r;
    } else {
        return *(const uint4*)((const uint16_t*)p + off);
    }
}

// ---------------------------------------------------------------------------
// Mask canonicalizer (mask is bool in the reference; encoding auto-detected).
// Output: int32[4096], nonzero = masked. One block.
// ---------------------------------------------------------------------------
__global__ __launch_bounds__(256) void mask_canon(
    const void* __restrict__ raw, int* __restrict__ canon)
{
    __shared__ int flags[3];  // [0]=byte evidence [1]=f32 evidence [2]=odd nonzero
    const uint32_t* w = (const uint32_t*)raw;
    const uint8_t* b8 = (const uint8_t*)raw;
    const int t = threadIdx.x;
    if (t < 3) flags[t] = 0;
    __syncthreads();
    int fbyte = 0, ff32 = 0, fodd = 0;
    for (int i = t; i < 1024; i += 256) {
        uint32_t v = w[i];
        if (v != 0u && v != 1u && v != 0x3F800000u) fbyte = 1;
        if (v == 0x3F800000u) ff32 = 1;
        if ((i & 1) && v != 0u) fodd = 1;
    }
    if (fbyte) atomicOr(&flags[0], 1);
    if (ff32)  atomicOr(&flags[1], 1);
    if (fodd)  atomicOr(&flags[2], 1);
    __syncthreads();
    int mode;  // 0 = word (int32/fp32), 1 = byte, 2 = int64
    if (flags[0]) mode = 1;
    else if (flags[1]) mode = 0;
    else if (!flags[2]) mode = 2;
    else mode = 0;
    for (int k = t; k < 4096; k += 256) {
        int val;
        if (mode == 1)      val = (b8[k] != 0);
        else if (mode == 2) val = (w[2 * k] != 0u);
        else                val = (w[k] != 0u);
        canon[k] = val;
    }
}

// ---------------------------------------------------------------------------
// NT GEMM: C[m,n] = sum_k A[m,k]*B[n,k]. 64x64 tile, BK=32, 4 waves in 2x2.
// AF32/BF32: operand element type (fp32 converted to bf16 at staging, or bf16).
// CM 0: fp32 row-major (M,N)
// CM 1: bf16 (B,H,T,DH) head-major  CM 2: bf16 (B,H,DH,T) head-major-transposed
// ---------------------------------------------------------------------------
template<int AF32, int BF32, int CM>
__global__ __launch_bounds__(256) void gemm_nt(
    const void* __restrict__ Av, const void* __restrict__ Bv,
    void* __restrict__ Cv, int M, int N, int K)
{
    __shared__ alignas(16) uint16_t As[64][40];  // +8 pad; 80B rows (16B-mult)
    __shared__ alignas(16) uint16_t Bs[64][40];

    const int t = threadIdx.x;
    const int lane = t & 63;
    const int wave = t >> 6;
    const int lrow = lane & 15;
    const int quad = lane >> 4;
    const int wr = (wave >> 1) * 32;
    const int wc = (wave & 1) * 32;
    const int bm = blockIdx.x, bn = blockIdx.y;

    const int lr = t >> 2;        // staging row 0..63
    const int lc = (t & 3) * 8;   // staging col {0,8,16,24}

    const size_t aoff = (size_t)(bm * 64 + lr) * K + lc;
    const size_t boff = (size_t)(bn * 64 + lr) * K + lc;

    const f32x4 fz = {0.f, 0.f, 0.f, 0.f};
    f32x4 acc00 = fz, acc01 = fz, acc10 = fz, acc11 = fz;

    for (int k0 = 0; k0 < K; k0 += 32) {
        uint4 av = load8<AF32>(Av, aoff + k0);
        uint4 bv = load8<BF32>(Bv, boff + k0);
        __syncthreads();  // prior iter's LDS reads complete before overwrite
        *(uint4*)(&As[lr][lc]) = av;
        *(uint4*)(&Bs[lr][lc]) = bv;
        __syncthreads();
        short8 a0 = *(const short8*)(&As[wr + lrow][quad * 8]);
        short8 a1 = *(const short8*)(&As[wr + 16 + lrow][quad * 8]);
        short8 b0 = *(const short8*)(&Bs[wc + lrow][quad * 8]);
        short8 b1 = *(const short8*)(&Bs[wc + 16 + lrow][quad * 8]);
        acc00 = __builtin_amdgcn_mfma_f32_16x16x32_bf16(a0, b0, acc00, 0, 0, 0);
        acc01 = __builtin_amdgcn_mfma_f32_16x16x32_bf16(a0, b1, acc01, 0, 0, 0);
        acc10 = __builtin_amdgcn_mfma_f32_16x16x32_bf16(a1, b0, acc10, 0, 0, 0);
        acc11 = __builtin_amdgcn_mfma_f32_16x16x32_bf16(a1, b1, acc11, 0, 0, 0);
    }

    f32x4 accs[2][2] = {{acc00, acc01}, {acc10, acc11}};
#pragma unroll
    for (int mi = 0; mi < 2; ++mi)
#pragma unroll
        for (int ni = 0; ni < 2; ++ni)
#pragma unroll
            for (int r = 0; r < 4; ++r) {
                // verified C/D map: row = quad*4 + reg, col = lane&15
                int m = bm * 64 + wr + mi * 16 + quad * 4 + r;
                int n = bn * 64 + wc + ni * 16 + lrow;
                float val = accs[mi][ni][r];
                if (CM == 0) {
                    ((float*)Cv)[(size_t)m * N + n] = val;
                } else {
                    int b = m >> 10, tt = m & 1023, hh = n >> 6, d = n & 63;
                    size_t idx = (CM == 1)
                        ? (((size_t)b * 16 + hh) * 1024 + tt) * 64 + d
                        : (((size_t)b * 16 + hh) * 64 + d) * 1024 + tt;
                    ((uint16_t*)Cv)[idx] = f2bf(val);
                }
            }
}

// ---------------------------------------------------------------------------
// Flash attention with relative-position logits (pos slab computed in-block).
// Grid: B*H*(T/64) = 1024 blocks, 256 thr = 4 waves; each wave owns 16 q rows.
// Prologue: stage pos_emb (257x64 fp32 -> bf16 LDS), per-wave MFMA computes
//   Qpos_l[64][272 used] = Q_blk @ pos_emb^T into LDS (bf16).
// NOTE: Qpos_l row width MUST be >= 272 — the nt=0..16 slab loop writes cols
//   up to 271 (cols 257..271 are zero padding). At [64][264] the tail writes
//   wrapped into the next row's rel=0..7 entries, zeroing valid pos logits for
//   all far-past keys (k-q <= -121) — the round-2/3 0.042 absmax bug.
// Main loop (32 keys/iter): S = Q Kh^T (4 MFMA) + gather(Qpos_l) + mask,
//   online softmax (shfl over 16-lane groups), P->LDS->A-layout, PV (4 MFMA).
// Output: comb (B*T, D) fp32 row-major, col = h*64+d.
// ---------------------------------------------------------------------------
__global__ __launch_bounds__(256) void flash_attn(
    const uint16_t* __restrict__ Qh, const uint16_t* __restrict__ Kh,
    const uint16_t* __restrict__ Vt, const float* __restrict__ pos,
    const int* __restrict__ mask, float* __restrict__ comb)
{
    const int blk = blockIdx.x;     // 0..1023
    const int bh = blk >> 4;        // b*16+h
    const int qt = blk & 15;
    const int b = bh >> 4;
    const int h = bh & 15;
    const int t = threadIdx.x;
    const int lane = t & 63;
    const int wave = t >> 6;
    const int lrow = lane & 15;
    const int quad = lane >> 4;
    const int qb = qt * 64 + wave * 16;  // wave's q base within (b,h)

    __shared__ alignas(16) uint16_t pos_s[272][72];   // 257 rows used, +pad
    __shared__ alignas(16) uint16_t Qpos_l[64][280];  // cols 0..256 used, 272 written
    __shared__ alignas(16) uint16_t Pl[4][16][40];    // per-wave P tile

    // ---- stage pos_emb -> LDS (bf16), zero tail rows ----
    for (int i = t; i < 272 * 8; i += 256) {
        int row = i >> 3, seg = (i & 7) * 8;
        uint4 val = {0u, 0u, 0u, 0u};
        if (row < 257) val = load8<1>(pos, (size_t)row * 64 + seg);
        *(uint4*)(&pos_s[row][seg]) = val;
    }

    const uint16_t* Qp = Qh + ((size_t)bh * 1024 + qb) * 64;
    short8 aq0 = *(const short8*)(Qp + (size_t)lrow * 64 + quad * 8);
    short8 aq1 = *(const short8*)(Qp + (size_t)lrow * 64 + 32 + quad * 8);

    __syncthreads();  // pos_s ready

    const f32x4 fz = {0.f, 0.f, 0.f, 0.f};

    // ---- prologue: this wave's 16x257 pos-logit slab (each wave writes and
    //      later reads only its own 16 rows, so no barrier needed after) ----
#pragma unroll 4
    for (int nt = 0; nt < 17; ++nt) {
        short8 pb0 = *(const short8*)(&pos_s[nt * 16 + lrow][quad * 8]);
        short8 pb1 = *(const short8*)(&pos_s[nt * 16 + lrow][32 + quad * 8]);
        f32x4 c = __builtin_amdgcn_mfma_f32_16x16x32_bf16(aq0, pb0, fz, 0, 0, 0);
        c = __builtin_amdgcn_mfma_f32_16x16x32_bf16(aq1, pb1, c, 0, 0, 0);
#pragma unroll
        for (int r = 0; r < 4; ++r)
            Qpos_l[wave * 16 + quad * 4 + r][nt * 16 + lrow] = f2bf(c[r]);
    }

    const uint16_t* Kp = Kh + (size_t)bh * 65536;
    const uint16_t* Vp = Vt + (size_t)bh * 65536;
    const int* mk = mask + b * 1024;

    f32x4 o[4] = {fz, fz, fz, fz};
    float mrun[4] = {-1e30f, -1e30f, -1e30f, -1e30f};
    float lrun[4] = {0.f, 0.f, 0.f, 0.f};

    for (int kb = 0; kb < 1024; kb += 32) {
        short8 k00 = *(const short8*)(Kp + (size_t)(kb + lrow) * 64 + quad * 8);
        short8 k01 = *(const short8*)(Kp + (size_t)(kb + lrow) * 64 + 32 + quad * 8);
        short8 k10 = *(const short8*)(Kp + (size_t)(kb + 16 + lrow) * 64 + quad * 8);
        short8 k11 = *(const short8*)(Kp + (size_t)(kb + 16 + lrow) * 64 + 32 + quad * 8);
        f32x4 s0 = __builtin_amdgcn_mfma_f32_16x16x32_bf16(aq0, k00, fz, 0, 0, 0);
        s0 = __builtin_amdgcn_mfma_f32_16x16x32_bf16(aq1, k01, s0, 0, 0, 0);
        f32x4 s1 = __builtin_amdgcn_mfma_f32_16x16x32_bf16(aq0, k10, fz, 0, 0, 0);
        s1 = __builtin_amdgcn_mfma_f32_16x16x32_bf16(aq1, k11, s1, 0, 0, 0);

        const int key0 = kb + lrow, key1 = kb + 16 + lrow;
        const bool msk0 = (mk[key0] != 0), msk1 = (mk[key1] != 0);

        float mx[4];
#pragma unroll
        for (int r = 0; r < 4; ++r) {
            int q = qb + quad * 4 + r;            // 0..1023 within (b,h)
            int ql = q & 63;                       // row in Qpos_l
            int r0 = min(max(key0 - q, -128), 128) + 128;
            int r1 = min(max(key1 - q, -128), 128) + 128;
            float p0 = bf2f(Qpos_l[ql][r0]);
            float p1 = bf2f(Qpos_l[ql][r1]);
            s0[r] = msk0 ? -1e30f : (s0[r] + p0) * 0.125f;
            s1[r] = msk1 ? -1e30f : (s1[r] + p1) * 0.125f;
            mx[r] = fmaxf(s0[r], s1[r]);
        }
#pragma unroll
        for (int off = 1; off < 16; off <<= 1)
#pragma unroll
            for (int r = 0; r < 4; ++r)
                mx[r] = fmaxf(mx[r], __shfl_xor(mx[r], off));

        float al[4], rs[4];
#pragma unroll
        for (int r = 0; r < 4; ++r) {
            float mn = fmaxf(mrun[r], mx[r]);
            al[r] = __expf(mrun[r] - mn);
            mrun[r] = mn;
            s0[r] = __expf(s0[r] - mn);
            s1[r] = __expf(s1[r] - mn);
            rs[r] = s0[r] + s1[r];
        }
#pragma unroll
        for (int off = 1; off < 16; off <<= 1)
#pragma unroll
            for (int r = 0; r < 4; ++r)
                rs[r] += __shfl_xor(rs[r], off);
#pragma unroll
        for (int r = 0; r < 4; ++r) {
            lrun[r] = lrun[r] * al[r] + rs[r];
            o[0][r] *= al[r]; o[1][r] *= al[r]; o[2][r] *= al[r]; o[3][r] *= al[r];
        }

        // P: C-layout -> per-wave LDS -> A-layout (in-order DS, same wave)
#pragma unroll
        for (int r = 0; r < 4; ++r) {
            Pl[wave][quad * 4 + r][lrow]      = f2bf(s0[r]);
            Pl[wave][quad * 4 + r][16 + lrow] = f2bf(s1[r]);
        }
        short8 ap = *(const short8*)(&Pl[wave][lrow][quad * 8]);

#pragma unroll
        for (int dt = 0; dt < 4; ++dt) {
            short8 bv = *(const short8*)(Vp + (size_t)(dt * 16 + lrow) * 1024 + kb + quad * 8);
            o[dt] = __builtin_amdgcn_mfma_f32_16x16x32_bf16(ap, bv, o[dt], 0, 0, 0);
        }
    }

    float inv[4];
#pragma unroll
    for (int r = 0; r < 4; ++r) inv[r] = 1.0f / lrun[r];

#pragma unroll
    for (int dt = 0; dt < 4; ++dt)
#pragma unroll
        for (int r = 0; r < 4; ++r) {
            size_t row = (size_t)b * 1024 + qb + quad * 4 + r;
            size_t col = (size_t)h * 64 + dt * 16 + lrow;
            comb[row * 1024 + col] = o[dt][r] * inv[r];
        }
}

// ---------------------------------------------------------------------------
// Inputs: x_q,x_k,x_v (fp32 B,T,D), mask (bool 4096, encoding auto-detected),
// Wq,Wk,Wv,Wo (fp32 D,D), pos_emb (fp32 257,64). Output: fp32 (B,T,D).
// ---------------------------------------------------------------------------
extern "C" void kernel_launch(void* const* d_in, const int* in_sizes, int n_in,
                              void* d_out, int out_size, void* d_ws, size_t ws_size,
                              hipStream_t stream)
{
    const float* x_q = (const float*)d_in[0];
    const float* x_k = (const float*)d_in[1];
    const float* x_v = (const float*)d_in[2];
    const void*  msk = d_in[3];
    const float* Wq  = (const float*)d_in[4];
    const float* Wk  = (const float*)d_in[5];
    const float* Wv  = (const float*)d_in[6];
    const float* Wo  = (const float*)d_in[7];
    const float* pos = (const float*)d_in[8];

    char* ws = (char*)d_ws;
    const size_t MB8 = 8388608;                        // 65536*64*2 bytes
    uint16_t* Qh    = (uint16_t*)(ws + 0 * MB8);       // (B,H,T,DH) bf16
    uint16_t* Khd   = (uint16_t*)(ws + 1 * MB8);       // (B,H,T,DH) bf16
    uint16_t* Vt    = (uint16_t*)(ws + 2 * MB8);       // (B,H,DH,T) bf16
    float*    comb  = (float*)(ws + 3 * MB8);          // (B*T, D) fp32 = 16MB
    int*      canon = (int*)(ws + 5 * MB8);            // mask int32[4096]

    dim3 blk(256);

    mask_canon<<<dim3(1), blk, 0, stream>>>(msk, canon);

    // Projections: (4096x1024) @ (1024x1024)^T, fp32 in -> bf16 head-major out
    gemm_nt<1, 1, 1><<<dim3(64, 16), blk, 0, stream>>>(x_q, Wq, Qh,  4096, 1024, 1024);
    gemm_nt<1, 1, 1><<<dim3(64, 16), blk, 0, stream>>>(x_k, Wk, Khd, 4096, 1024, 1024);
    gemm_nt<1, 1, 2><<<dim3(64, 16), blk, 0, stream>>>(x_v, Wv, Vt,  4096, 1024, 1024);

    // Flash attention (pos slab computed per block) -> comb (B*T, D) fp32
    flash_attn<<<dim3(1024), blk, 0, stream>>>(Qh, Khd, Vt, pos, canon, comb);

    // Output projection: comb(fp32) @ Wo(fp32)^T -> fp32 d_out
    gemm_nt<1, 1, 0><<<dim3(64, 16), blk, 0, stream>>>(comb, Wo, d_out, 4096, 1024, 1024);
}

// Round 5
// 335.554 us; speedup vs baseline: 1.1406x; 1.1406x over previous
//
#include <hip/hip_runtime.h>
#include <hip/hip_bf16.h>
#include <stdint.h>

typedef __attribute__((ext_vector_type(8))) short short8;  // 8 bf16 (4 VGPRs)
typedef __attribute__((ext_vector_type(4))) float f32x4;   // 4 fp32 acc

__device__ __forceinline__ uint16_t f2bf(float f) {
    union { float f; uint32_t u; } v; v.f = f;
    uint32_t r = v.u + 0x7FFF + ((v.u >> 16) & 1);  // RNE
    return (uint16_t)(r >> 16);
}
__device__ __forceinline__ float bf2f(uint16_t u) {
    union { uint32_t u; float f; } v; v.u = ((uint32_t)u) << 16;
    return v.f;
}

// Load 8 consecutive elements at flat offset `off`, return packed bf16x8.
template<int F32>
__device__ __forceinline__ uint4 load8(const void* p, size_t off) {
    if (F32) {
        const float* f = (const float*)p + off;
        float4 f0 = *(const float4*)f;
        float4 f1 = *(const float4*)(f + 4);
        uint4 r;
        r.x = (uint32_t)f2bf(f0.x) | ((uint32_t)f2bf(f0.y) << 16);
        r.y = (uint32_t)f2bf(f0.z) | ((uint32_t)f2bf(f0.w) << 16);
        r.z = (uint32_t)f2bf(f1.x) | ((uint32_t)f2bf(f1.y) << 16);
        r.w = (uint32_t)f2bf(f1.z) | ((uint32_t)f2bf(f1.w) << 16);
        return r;
    } else {
        return *(const uint4*)((const uint16_t*)p + off);
    }
}

// global -> LDS direct DMA, 16 B/lane; LDS dest = wave-uniform base + lane*16.
#define GLDS(gp, lp) __builtin_amdgcn_global_load_lds( \
    (const __attribute__((address_space(1))) void*)(gp), \
    (__attribute__((address_space(3))) void*)(lp), 16, 0, 0)

// ---------------------------------------------------------------------------
// Mask canonicalizer (bool in the reference; encoding auto-detected).
// ---------------------------------------------------------------------------
__global__ __launch_bounds__(256) void mask_canon(
    const void* __restrict__ raw, int* __restrict__ canon)
{
    __shared__ int flags[3];
    const uint32_t* w = (const uint32_t*)raw;
    const uint8_t* b8 = (const uint8_t*)raw;
    const int t = threadIdx.x;
    if (t < 3) flags[t] = 0;
    __syncthreads();
    int fbyte = 0, ff32 = 0, fodd = 0;
    for (int i = t; i < 1024; i += 256) {
        uint32_t v = w[i];
        if (v != 0u && v != 1u && v != 0x3F800000u) fbyte = 1;
        if (v == 0x3F800000u) ff32 = 1;
        if ((i & 1) && v != 0u) fodd = 1;
    }
    if (fbyte) atomicOr(&flags[0], 1);
    if (ff32)  atomicOr(&flags[1], 1);
    if (fodd)  atomicOr(&flags[2], 1);
    __syncthreads();
    int mode;  // 0 = word, 1 = byte, 2 = int64
    if (flags[0]) mode = 1;
    else if (flags[1]) mode = 0;
    else if (!flags[2]) mode = 2;
    else mode = 0;
    for (int k = t; k < 4096; k += 256) {
        int val;
        if (mode == 1)      val = (b8[k] != 0);
        else if (mode == 2) val = (w[2 * k] != 0u);
        else                val = (w[k] != 0u);
        canon[k] = val;
    }
}

// ---------------------------------------------------------------------------
// Bulk fp32 -> bf16 conversion over up to 8 segments (one dispatch).
// ---------------------------------------------------------------------------
struct CvtSeg { const float* s; uint16_t* d; int n8; };
struct CvtArgs { CvtSeg seg[8]; int nseg; };

__global__ __launch_bounds__(256) void cvt_bf16(CvtArgs a)
{
    const int tid = blockIdx.x * 256 + threadIdx.x;
    const int stride = gridDim.x * 256;
    for (int s = 0; s < a.nseg; ++s) {
        const float* src = a.seg[s].s;
        uint16_t* dst = a.seg[s].d;
        const int n8 = a.seg[s].n8;
        for (int i = tid; i < n8; i += stride)
            *(uint4*)(dst + (size_t)i * 8) = load8<1>(src, (size_t)i * 8);
    }
}

// ---------------------------------------------------------------------------
// 128x128-tile NT GEMM body (m97 structure): BK=32, 256 thr = 4 waves in 2x2,
// each wave 64x64 (16 MFMA/iter), B (and A when AF32=0) staged via
// global_load_lds dwordx4. LDS tiles 128x32 bf16 UNPADDED (glds lane-order
// constraint). AF32=1: A is fp32, staged via vector-load + convert + ds_write.
// cm 0: C fp32 row-major; cm 1: bf16 (B,H,T,DH); cm 2: bf16 (B,H,DH,T).
// ---------------------------------------------------------------------------
template<int AF32>
__device__ __forceinline__ void gemm128_body(
    const void* __restrict__ A, const uint16_t* __restrict__ B,
    void* __restrict__ C, int M, int N, int K, int cm, int bm, int bn,
    uint16_t* As, uint16_t* Bs)
{
    const int t = threadIdx.x;
    const int lane = t & 63, wave = t >> 6;
    const int lrow = lane & 15, quad = lane >> 4;
    const int wr = (wave >> 1) * 64, wc = (wave & 1) * 64;

    // glds mapping: byte off = wave*1024 + j*4096 + lane*16
    //   -> row = wave*16 + j*64 + lane/4, colseg = (lane&3)*8
    const int g_row = wave * 16 + (lane >> 2);
    const int g_col = (lane & 3) * 8;
    // AF32 staging mapping: thread t -> row t>>1, col half (t&1)*16
    const int s_row = t >> 1, s_col = (t & 1) * 16;

    const uint16_t* Ab = (const uint16_t*)A;
    const float*    Af = (const float*)A;

    const f32x4 fz = {0.f, 0.f, 0.f, 0.f};
    f32x4 acc[4][4];
#pragma unroll
    for (int i = 0; i < 4; ++i)
#pragma unroll
        for (int j = 0; j < 4; ++j) acc[i][j] = fz;

    for (int k0 = 0; k0 < K; k0 += 32) {
        uint4 lo, hi;
        if (AF32) {  // hoist global loads above the barrier
            size_t off = (size_t)(bm * 128 + s_row) * K + k0 + s_col;
            lo = load8<1>(Af, off);
            hi = load8<1>(Af, off + 8);
        }
        __syncthreads();  // all waves done reading previous LDS contents
        if (AF32) {
            *(uint4*)(As + s_row * 32 + s_col)     = lo;
            *(uint4*)(As + s_row * 32 + s_col + 8) = hi;
        } else {
            GLDS(Ab + (size_t)(bm * 128 + g_row) * K + k0 + g_col,      As + wave * 512);
            GLDS(Ab + (size_t)(bm * 128 + g_row + 64) * K + k0 + g_col, As + wave * 512 + 2048);
        }
        GLDS(B + (size_t)(bn * 128 + g_row) * K + k0 + g_col,      Bs + wave * 512);
        GLDS(B + (size_t)(bn * 128 + g_row + 64) * K + k0 + g_col, Bs + wave * 512 + 2048);
        __syncthreads();  // staged (compiler drains vmcnt/lgkmcnt before barrier)

        short8 a[4], b[4];
#pragma unroll
        for (int i = 0; i < 4; ++i)
            a[i] = *(const short8*)(As + (wr + i * 16 + lrow) * 32 + quad * 8);
#pragma unroll
        for (int j = 0; j < 4; ++j)
            b[j] = *(const short8*)(Bs + (wc + j * 16 + lrow) * 32 + quad * 8);
#pragma unroll
        for (int i = 0; i < 4; ++i)
#pragma unroll
            for (int j = 0; j < 4; ++j)
                acc[i][j] = __builtin_amdgcn_mfma_f32_16x16x32_bf16(a[i], b[j], acc[i][j], 0, 0, 0);
    }

#pragma unroll
    for (int i = 0; i < 4; ++i)
#pragma unroll
        for (int j = 0; j < 4; ++j)
#pragma unroll
            for (int r = 0; r < 4; ++r) {
                // verified C/D map: row = quad*4 + reg, col = lane&15
                int m = bm * 128 + wr + i * 16 + quad * 4 + r;
                int n = bn * 128 + wc + j * 16 + lrow;
                float val = acc[i][j][r];
                if (cm == 0) {
                    ((float*)C)[(size_t)m * N + n] = val;
                } else {
                    int bb = m >> 10, tt = m & 1023, hh = n >> 6, d = n & 63;
                    size_t idx = (cm == 1)
                        ? (((size_t)bb * 16 + hh) * 1024 + tt) * 64 + d
                        : (((size_t)bb * 16 + hh) * 64 + d) * 1024 + tt;
                    ((uint16_t*)C)[idx] = f2bf(val);
                }
            }
}

// Fused Q/K/V projections: gridDim.z selects (x, W, out, layout). 768 blocks.
template<int AF32>
__global__ __launch_bounds__(256) void gemm128_qkv(
    const void* __restrict__ xq, const void* __restrict__ xk, const void* __restrict__ xv,
    const uint16_t* __restrict__ Wq, const uint16_t* __restrict__ Wk, const uint16_t* __restrict__ Wv,
    uint16_t* __restrict__ Qh, uint16_t* __restrict__ Khd, uint16_t* __restrict__ Vt)
{
    __shared__ alignas(16) uint16_t As[128 * 32];
    __shared__ alignas(16) uint16_t Bs[128 * 32];
    const int z = blockIdx.z;
    const void* A = (z == 0) ? xq : (z == 1) ? xk : xv;
    const uint16_t* B = (z == 0) ? Wq : (z == 1) ? Wk : Wv;
    void* C = (z == 0) ? (void*)Qh : (z == 1) ? (void*)Khd : (void*)Vt;
    const int cm = (z == 2) ? 2 : 1;
    gemm128_body<AF32>(A, B, C, 4096, 1024, 1024, cm, blockIdx.x, blockIdx.y, As, Bs);
}

__global__ __launch_bounds__(256) void gemm128_single(
    const void* __restrict__ A, const uint16_t* __restrict__ B, void* __restrict__ C,
    int M, int N, int K, int cm)
{
    __shared__ alignas(16) uint16_t As[128 * 32];
    __shared__ alignas(16) uint16_t Bs[128 * 32];
    gemm128_body<0>(A, B, C, M, N, K, cm, blockIdx.x, blockIdx.y, As, Bs);
}

// ---------------------------------------------------------------------------
// Flash attention with relative-position logits (pos slab computed in-block).
// Identical to the round-4 passing kernel except: pos input is bf16 (pre-
// converted) and comb output is bf16 (feeds the glds path of the final GEMM).
// Qpos_l row width MUST be >= 272 (nt=0..16 writes cols up to 271).
// ---------------------------------------------------------------------------
__global__ __launch_bounds__(256) void flash_attn(
    const uint16_t* __restrict__ Qh, const uint16_t* __restrict__ Kh,
    const uint16_t* __restrict__ Vt, const uint16_t* __restrict__ pos,
    const int* __restrict__ mask, uint16_t* __restrict__ comb)
{
    const int blk = blockIdx.x;     // 0..1023
    const int bh = blk >> 4;        // b*16+h
    const int qt = blk & 15;
    const int b = bh >> 4;
    const int h = bh & 15;
    const int t = threadIdx.x;
    const int lane = t & 63;
    const int wave = t >> 6;
    const int lrow = lane & 15;
    const int quad = lane >> 4;
    const int qb = qt * 64 + wave * 16;

    __shared__ alignas(16) uint16_t pos_s[272][72];
    __shared__ alignas(16) uint16_t Qpos_l[64][280];
    __shared__ alignas(16) uint16_t Pl[4][16][40];

    for (int i = t; i < 272 * 8; i += 256) {
        int row = i >> 3, seg = (i & 7) * 8;
        uint4 val = {0u, 0u, 0u, 0u};
        if (row < 257) val = load8<0>(pos, (size_t)row * 64 + seg);
        *(uint4*)(&pos_s[row][seg]) = val;
    }

    const uint16_t* Qp = Qh + ((size_t)bh * 1024 + qb) * 64;
    short8 aq0 = *(const short8*)(Qp + (size_t)lrow * 64 + quad * 8);
    short8 aq1 = *(const short8*)(Qp + (size_t)lrow * 64 + 32 + quad * 8);

    __syncthreads();

    const f32x4 fz = {0.f, 0.f, 0.f, 0.f};

#pragma unroll 4
    for (int nt = 0; nt < 17; ++nt) {
        short8 pb0 = *(const short8*)(&pos_s[nt * 16 + lrow][quad * 8]);
        short8 pb1 = *(const short8*)(&pos_s[nt * 16 + lrow][32 + quad * 8]);
        f32x4 c = __builtin_amdgcn_mfma_f32_16x16x32_bf16(aq0, pb0, fz, 0, 0, 0);
        c = __builtin_amdgcn_mfma_f32_16x16x32_bf16(aq1, pb1, c, 0, 0, 0);
#pragma unroll
        for (int r = 0; r < 4; ++r)
            Qpos_l[wave * 16 + quad * 4 + r][nt * 16 + lrow] = f2bf(c[r]);
    }

    const uint16_t* Kp = Kh + (size_t)bh * 65536;
    const uint16_t* Vp = Vt + (size_t)bh * 65536;
    const int* mk = mask + b * 1024;

    f32x4 o[4] = {fz, fz, fz, fz};
    float mrun[4] = {-1e30f, -1e30f, -1e30f, -1e30f};
    float lrun[4] = {0.f, 0.f, 0.f, 0.f};

    for (int kb = 0; kb < 1024; kb += 32) {
        short8 k00 = *(const short8*)(Kp + (size_t)(kb + lrow) * 64 + quad * 8);
        short8 k01 = *(const short8*)(Kp + (size_t)(kb + lrow) * 64 + 32 + quad * 8);
        short8 k10 = *(const short8*)(Kp + (size_t)(kb + 16 + lrow) * 64 + quad * 8);
        short8 k11 = *(const short8*)(Kp + (size_t)(kb + 16 + lrow) * 64 + 32 + quad * 8);
        f32x4 s0 = __builtin_amdgcn_mfma_f32_16x16x32_bf16(aq0, k00, fz, 0, 0, 0);
        s0 = __builtin_amdgcn_mfma_f32_16x16x32_bf16(aq1, k01, s0, 0, 0, 0);
        f32x4 s1 = __builtin_amdgcn_mfma_f32_16x16x32_bf16(aq0, k10, fz, 0, 0, 0);
        s1 = __builtin_amdgcn_mfma_f32_16x16x32_bf16(aq1, k11, s1, 0, 0, 0);

        const int key0 = kb + lrow, key1 = kb + 16 + lrow;
        const bool msk0 = (mk[key0] != 0), msk1 = (mk[key1] != 0);

        float mx[4];
#pragma unroll
        for (int r = 0; r < 4; ++r) {
            int q = qb + quad * 4 + r;
            int ql = q & 63;
            int r0 = min(max(key0 - q, -128), 128) + 128;
            int r1 = min(max(key1 - q, -128), 128) + 128;
            float p0 = bf2f(Qpos_l[ql][r0]);
            float p1 = bf2f(Qpos_l[ql][r1]);
            s0[r] = msk0 ? -1e30f : (s0[r] + p0) * 0.125f;
            s1[r] = msk1 ? -1e30f : (s1[r] + p1) * 0.125f;
            mx[r] = fmaxf(s0[r], s1[r]);
        }
#pragma unroll
        for (int off = 1; off < 16; off <<= 1)
#pragma unroll
            for (int r = 0; r < 4; ++r)
                mx[r] = fmaxf(mx[r], __shfl_xor(mx[r], off));

        float al[4], rs[4];
#pragma unroll
        for (int r = 0; r < 4; ++r) {
            float mn = fmaxf(mrun[r], mx[r]);
            al[r] = __expf(mrun[r] - mn);
            mrun[r] = mn;
            s0[r] = __expf(s0[r] - mn);
            s1[r] = __expf(s1[r] - mn);
            rs[r] = s0[r] + s1[r];
        }
#pragma unroll
        for (int off = 1; off < 16; off <<= 1)
#pragma unroll
            for (int r = 0; r < 4; ++r)
                rs[r] += __shfl_xor(rs[r], off);
#pragma unroll
        for (int r = 0; r < 4; ++r) {
            lrun[r] = lrun[r] * al[r] + rs[r];
            o[0][r] *= al[r]; o[1][r] *= al[r]; o[2][r] *= al[r]; o[3][r] *= al[r];
        }

#pragma unroll
        for (int r = 0; r < 4; ++r) {
            Pl[wave][quad * 4 + r][lrow]      = f2bf(s0[r]);
            Pl[wave][quad * 4 + r][16 + lrow] = f2bf(s1[r]);
        }
        short8 ap = *(const short8*)(&Pl[wave][lrow][quad * 8]);

#pragma unroll
        for (int dt = 0; dt < 4; ++dt) {
            short8 bv = *(const short8*)(Vp + (size_t)(dt * 16 + lrow) * 1024 + kb + quad * 8);
            o[dt] = __builtin_amdgcn_mfma_f32_16x16x32_bf16(ap, bv, o[dt], 0, 0, 0);
        }
    }

    float inv[4];
#pragma unroll
    for (int r = 0; r < 4; ++r) inv[r] = 1.0f / lrun[r];

#pragma unroll
    for (int dt = 0; dt < 4; ++dt)
#pragma unroll
        for (int r = 0; r < 4; ++r) {
            size_t row = (size_t)b * 1024 + qb + quad * 4 + r;
            size_t col = (size_t)h * 64 + dt * 16 + lrow;
            comb[row * 1024 + col] = f2bf(o[dt][r] * inv[r]);
        }
}

// ---------------------------------------------------------------------------
extern "C" void kernel_launch(void* const* d_in, const int* in_sizes, int n_in,
                              void* d_out, int out_size, void* d_ws, size_t ws_size,
                              hipStream_t stream)
{
    const float* x_q = (const float*)d_in[0];
    const float* x_k = (const float*)d_in[1];
    const float* x_v = (const float*)d_in[2];
    const void*  msk = d_in[3];
    const float* Wq  = (const float*)d_in[4];
    const float* Wk  = (const float*)d_in[5];
    const float* Wv  = (const float*)d_in[6];
    const float* Wo  = (const float*)d_in[7];
    const float* pos = (const float*)d_in[8];

    char* ws = (char*)d_ws;
    const size_t MB = 1u << 20;
    uint16_t* Qh  = (uint16_t*)(ws);            // (B,H,T,DH) bf16, 8 MB
    uint16_t* Khd = (uint16_t*)(ws + 8 * MB);   // (B,H,T,DH) bf16
    uint16_t* Vt  = (uint16_t*)(ws + 16 * MB);  // (B,H,DH,T) bf16

    const bool big = ws_size >= 60 * MB;  // constant per session -> graph-safe
    uint16_t *comb, *Wqb, *Wkb, *Wvb, *Wob, *posb;
    uint16_t *xqb = nullptr, *xkb = nullptr, *xvb = nullptr;
    int* canon;
    if (big) {
        xqb  = (uint16_t*)(ws + 24 * MB);
        xkb  = (uint16_t*)(ws + 32 * MB);
        xvb  = (uint16_t*)(ws + 40 * MB);
        Wqb  = (uint16_t*)(ws + 48 * MB);
        Wkb  = (uint16_t*)(ws + 50 * MB);
        Wvb  = (uint16_t*)(ws + 52 * MB);
        Wob  = (uint16_t*)(ws + 54 * MB);
        posb = (uint16_t*)(ws + 56 * MB);
        canon = (int*)(ws + 56 * MB + 65536);
        comb = xqb;  // xq_b dead after projections; flash runs after them
    } else {
        comb = (uint16_t*)(ws + 24 * MB);
        Wqb  = (uint16_t*)(ws + 32 * MB);
        Wkb  = (uint16_t*)(ws + 34 * MB);
        Wvb  = (uint16_t*)(ws + 36 * MB);
        Wob  = (uint16_t*)(ws + 38 * MB);
        posb = (uint16_t*)(ws + 40 * MB);
        canon = (int*)(ws + 40 * MB + 65536);
    }

    mask_canon<<<dim3(1), dim3(256), 0, stream>>>(msk, canon);

    CvtArgs ca{};
    int ns = 0;
    if (big) {
        ca.seg[ns++] = {x_q, xqb, 524288};
        ca.seg[ns++] = {x_k, xkb, 524288};
        ca.seg[ns++] = {x_v, xvb, 524288};
    }
    ca.seg[ns++] = {Wq, Wqb, 131072};
    ca.seg[ns++] = {Wk, Wkb, 131072};
    ca.seg[ns++] = {Wv, Wvb, 131072};
    ca.seg[ns++] = {Wo, Wob, 131072};
    ca.seg[ns++] = {pos, posb, 2056};   // 257*64/8
    ca.nseg = ns;
    cvt_bf16<<<dim3(256), dim3(256), 0, stream>>>(ca);

    // Fused Q/K/V projections: 32x8x3 = 768 blocks (~3/CU)
    if (big)
        gemm128_qkv<0><<<dim3(32, 8, 3), dim3(256), 0, stream>>>(
            xqb, xkb, xvb, Wqb, Wkb, Wvb, Qh, Khd, Vt);
    else
        gemm128_qkv<1><<<dim3(32, 8, 3), dim3(256), 0, stream>>>(
            x_q, x_k, x_v, Wqb, Wkb, Wvb, Qh, Khd, Vt);

    flash_attn<<<dim3(1024), dim3(256), 0, stream>>>(Qh, Khd, Vt, posb, canon, comb);

    // Output projection: comb(bf16) @ Wo_b^T -> fp32 d_out
    gemm128_single<<<dim3(32, 8), dim3(256), 0, stream>>>(
        comb, Wob, d_out, 4096, 1024, 1024, 0);
}